// Round 2
// baseline (510.148 us; speedup 1.0000x reference)
//
#include <hip/hip_runtime.h>

typedef __bf16 bf16x8 __attribute__((ext_vector_type(8)));
typedef __bf16 bf16x2 __attribute__((ext_vector_type(2)));
typedef float  f32x4  __attribute__((ext_vector_type(4)));

// sizes: E=4 B=32 CI=64 H=W=64 CO=128 OH=OW=62
// ws layout: [0, 64MiB) features bf16 NHWC [eb][y][x][i]
//            [64MiB, +576KiB) weights bf16 [e][tap][j][i]
#define FT_BYTES 67108864ull

__device__ __forceinline__ void gl2lds16(const void* g, void* l) {
    __builtin_amdgcn_global_load_lds(
        (const __attribute__((address_space(1))) void*)g,
        (__attribute__((address_space(3))) void*)l, 16, 0, 0);
}

// prepass 1: weight fp32 [e][i][j][tap] -> bf16 [e][tap][j][i]
// coalesced reads (idx contiguous in input), scattered 2B writes (L2-absorbed, 576KB)
__global__ void wt_prep(const float* __restrict__ w, __bf16* __restrict__ wt) {
    int idx = blockIdx.x * 256 + threadIdx.x;         // 294912 total
    float v = w[idx];
    int tap = idx % 9, r1 = idx / 9;
    int j = r1 & 127, r2 = r1 >> 7;
    int i = r2 & 63, e = r2 >> 6;
    wt[((e * 9 + tap) * 128 + j) * 64 + i] = (__bf16)v;
}

// prepass 2: features fp32 NCHW -> bf16 NHWC, one block per (e,b,y)
__global__ void ft_prep(const float* __restrict__ f, __bf16* __restrict__ ft) {
    __shared__ float s[64 * 65];                      // [i][x], +1 pad
    int eb = blockIdx.z * 32 + blockIdx.y, y = blockIdx.x;
    const float* src = f + (size_t)eb * 262144 + y * 64;
    int t = threadIdx.x;
    for (int r = 0; r < 4; ++r) {
        int f4 = r * 256 + t;                         // 1024 float4
        int i = f4 >> 4, x4 = (f4 & 15) * 4;
        float4 v = *(const float4*)(src + i * 4096 + x4);
        s[i * 65 + x4 + 0] = v.x; s[i * 65 + x4 + 1] = v.y;
        s[i * 65 + x4 + 2] = v.z; s[i * 65 + x4 + 3] = v.w;
    }
    __syncthreads();
    bf16x2* dst = (bf16x2*)(ft + (size_t)(eb * 64 + y) * 4096);
    for (int r = 0; r < 8; ++r) {
        int q = r * 256 + t;                          // 2048 bf16x2; q = x*32+ih
        int x = q >> 5, ih = q & 31;
        bf16x2 pv;
        pv.x = (__bf16)s[(2 * ih + 0) * 65 + x];
        pv.y = (__bf16)s[(2 * ih + 1) * 65 + x];
        dst[q] = pv;
    }
}

// main v2: per block (e,b,2-row group): out tile 128(j) x 128(p=2y*64x).
// Features: 4 input rows staged ONCE into LDS (32 KB, single barrier).
// Weights: fragments read directly from global (L2-resident, shared by all
// 992 blocks per e) -> K-loop has ZERO barriers; compiler interleaves
// global_load_dwordx4 with MFMA via fine-grained vmcnt (AITER-style).
__global__ __launch_bounds__(256, 3)
void conv_main(const __bf16* __restrict__ ft, const __bf16* __restrict__ wt,
               const float* __restrict__ bias, float* __restrict__ out) {
    __shared__ __align__(16) __bf16 sB[256 * 64];     // [p'=4y*64x][i] 32 KB
    const int e = blockIdx.z, b = blockIdx.y, y0 = blockIdx.x * 2;
    const int eb = e * 32 + b;
    const int t = threadIdx.x, lane = t & 63, w = t >> 6;
    const int wm = w >> 1, wn = w & 1;                // 2x2 waves over (M,N)
    const int q = lane >> 4, rm = lane & 15;

    // stage 4 feature rows y0..y0+3 (contiguous in NHWC): 2048 16B chunks,
    // chunk g of row r stored at slot g^(r&7) (bank swizzle)
    const __bf16* ftb = ft + (size_t)eb * 262144 + (size_t)y0 * 4096;
    for (int cc = 0; cc < 8; ++cc) {
        int C = (cc * 4 + w) * 64 + lane;             // chunk id 0..2047
        int r = C >> 3;
        int g = (lane & 7) ^ (r & 7);
        gl2lds16(ftb + r * 64 + g * 8, sB + C * 8);
    }
    __syncthreads();                                  // drains DMA (vmcnt 0), once

    f32x4 acc[4][4] = {};
    const __bf16* wte = wt + (size_t)e * 9 * 8192;

    for (int tap = 0; tap < 9; ++tap) {
        const int A = tap / 3, Bt = tap - A * 3;
        const __bf16* wtap = wte + tap * 8192;
        int rr[4];                                    // LDS row per n-frag
        for (int ni = 0; ni < 4; ++ni) {
            int n = wn * 64 + ni * 16 + rm;
            int px = n & 63, py = n >> 6;
            int xx = px + Bt; if (xx > 63) xx = 63;   // clamp feeds dead cols only
            rr[ni] = (A + py) * 64 + xx;
        }
        for (int kk = 0; kk < 2; ++kk) {
            const int kg = kk * 4;                    // 16B-chunk base: 0 or 4
            bf16x8 af[4], bq[4];
            for (int mi = 0; mi < 4; ++mi) {          // weights straight from L2
                int j = wm * 64 + mi * 16 + rm;
                af[mi] = *(const bf16x8*)(wtap + j * 64 + (kg + q) * 8);
            }
            for (int ni = 0; ni < 4; ++ni) {
                int ch = (kg + q) ^ (rr[ni] & 7);
                bq[ni] = *(const bf16x8*)(sB + rr[ni] * 64 + ch * 8);
            }
            for (int mi = 0; mi < 4; ++mi)
                for (int ni = 0; ni < 4; ++ni)
                    acc[mi][ni] = __builtin_amdgcn_mfma_f32_16x16x32_bf16(
                        af[mi], bq[ni], acc[mi][ni], 0, 0, 0);
        }
    }

    // epilogue: D layout col(n=p)=lane&15, row(m=j)=(lane>>4)*4+reg
    for (int mi = 0; mi < 4; ++mi) {
        for (int ni = 0; ni < 4; ++ni) {
            int p = wn * 64 + ni * 16 + rm;
            int py = p >> 6, px = p & 63;
            if (px >= 62) continue;                   // dead padding columns
            for (int vv = 0; vv < 4; ++vv) {
                int j = wm * 64 + mi * 16 + q * 4 + vv;
                float v = acc[mi][ni][vv] + bias[e * 128 + j];
                out[(((size_t)eb * 128 + j) * 62 + (y0 + py)) * 62 + px] = v;
            }
        }
    }
}

extern "C" void kernel_launch(void* const* d_in, const int* in_sizes, int n_in,
                              void* d_out, int out_size, void* d_ws, size_t ws_size,
                              hipStream_t stream) {
    const float* f    = (const float*)d_in[0];
    const float* wgt  = (const float*)d_in[1];
    const float* bias = (const float*)d_in[2];
    float* out = (float*)d_out;
    __bf16* ftw = (__bf16*)d_ws;
    __bf16* wtw = (__bf16*)((char*)d_ws + FT_BYTES);

    ft_prep<<<dim3(64, 32, 4), 256, 0, stream>>>(f, ftw);
    wt_prep<<<dim3(1152), 256, 0, stream>>>(wgt, wtw);
    conv_main<<<dim3(31, 32, 4), 256, 0, stream>>>(ftw, wtw, bias, out);
}